// Round 3
// baseline (246.560 us; speedup 1.0000x reference)
//
#include <hip/hip_runtime.h>
#include <hip/hip_bf16.h>

#define BB 16
#define NN 1024
#define DD 5
#define RH 8

typedef unsigned long long u64;
typedef __hip_bfloat16 bf16;

static __device__ __forceinline__ float tof(bf16 x) { return __bfloat162float(x); }

// flags layout (int) in ws: [0]=insane_cnt [1]=adj_non01 [2]=adj_nonpair [3]=adj_low3f80
#define N_PROBE_WORDS 8192

// ---------------------------------------------------------------- init
__global__ void k_init(int* flags, float* pooled) {
  int t = threadIdx.x;
  if (t < 8) flags[t] = 0;
  if (t < BB * DD) pooled[t] = 0.0f;
}

// ------------------------------------------------- float dtype probe
// Low 16 bits of each word decoded as bf16: sane exponent => bf16 storage,
// uniform-random exponent => these are f32 mantissa bits => f32 storage.
__global__ void k_probe_float(const unsigned int* __restrict__ w, int* flags) {
  int i = blockIdx.x * 256 + threadIdx.x;
  if (i >= N_PROBE_WORDS) return;
  unsigned int lo = w[i] & 0xFFFFu;
  int e = (int)((lo >> 7) & 0xFFu);
  bool sane = (lo == 0u) || (e >= 90 && e <= 150);
  u64 mask = __ballot(!sane);
  if ((threadIdx.x & 63) == 0) atomicAdd(&flags[0], (int)__popcll(mask));
}

// ------------------------------------------------- adjacency storage probe
__global__ void k_probe_adj(const unsigned int* __restrict__ w, int nwords, int* flags) {
  int idx = blockIdx.x * blockDim.x + threadIdx.x;
  int stride = gridDim.x * blockDim.x;
  int non01 = 0, nonpair = 0, low3 = 0;
  for (int i = idx; i < nwords; i += stride) {
    unsigned int x = w[i];
    unsigned int lo = x & 0xFFFFu, hi = x >> 16;
    non01 |= (x > 1u);
    nonpair |= !((lo == 0u || lo == 0x3F80u) && (hi == 0u || hi == 0x3F80u));
    low3 |= (lo == 0x3F80u);
  }
  if (non01) atomicOr(&flags[1], 1);
  if (nonpair) atomicOr(&flags[2], 1);
  if (low3) atomicOr(&flags[3], 1);
}

// ------------------------------------------------- convert all float inputs
struct CvtArgs {
  const void* src[14];
  float* dst[14];
  int n[14];
};
__global__ void k_cvt(CvtArgs a, const int* __restrict__ flags) {
  int which = blockIdx.y;
  int n = a.n[which];
  int i = blockIdx.x * 256 + threadIdx.x;
  if (i >= n) return;
  bool isf32 = flags[0] > (N_PROBE_WORDS / 4);
  float v = isf32 ? ((const float*)a.src[which])[i]
                  : tof(((const bf16*)a.src[which])[i]);
  a.dst[which][i] = v;
}

// ---------------------------------------------------------------- pack
// adjbits[(b*N+i)*16 + w] = 64 adjacency bits j = w*64 .. w*64+63
__global__ void k_pack(const void* __restrict__ adj, const int* __restrict__ flags,
                       u64* __restrict__ adjbits) {
  int gid = blockIdx.x * blockDim.x + threadIdx.x;
  if (gid >= BB * NN * 16) return;
  int w = gid & 15;
  long long row = gid >> 4;  // b*N + i
  long long base = row * NN + w * 64;
  // mode: 0=int32, 1=byte, 2=bf16, 3=f32
  int mode;
  if (!flags[1]) mode = 0;
  else if (!flags[2]) mode = flags[3] ? 2 : 3;
  else mode = 1;
  u64 bits = 0;
  if (mode == 0) {
    const unsigned int* p = (const unsigned int*)adj + base;
    for (int t = 0; t < 64; ++t) if (p[t]) bits |= 1ull << t;
  } else if (mode == 1) {
    const unsigned char* p = (const unsigned char*)adj + base;
    for (int t = 0; t < 64; ++t) if (p[t]) bits |= 1ull << t;
  } else if (mode == 2) {
    const unsigned short* p = (const unsigned short*)adj + base;
    for (int t = 0; t < 64; ++t) if (p[t]) bits |= 1ull << t;
  } else {
    const float* p = (const float*)adj + base;
    for (int t = 0; t < 64; ++t) if (p[t] != 0.0f) bits |= 1ull << t;
  }
  adjbits[gid] = bits;
}

// -------------------------------------------------------------- two-hop
__global__ void k_twohop(const u64* __restrict__ adjbits, u64* __restrict__ neighbits) {
  int gid = blockIdx.x * blockDim.x + threadIdx.x;
  if (gid >= BB * NN * 16) return;
  int w = gid & 15;
  int row = gid >> 4;       // b*N + i
  int b = row >> 10;
  int i = row & (NN - 1);
  const u64* rowp = adjbits + (size_t)row * 16;
  u64 acc = rowp[w];
  if ((i >> 6) == w) acc |= 1ull << (i & 63);
  const u64* basep = adjbits + (size_t)b * NN * 16;
  for (int sw = 0; sw < 16; ++sw) {
    u64 bits = rowp[sw];
    while (bits) {
      int t = __ffsll(bits) - 1;
      bits &= bits - 1;
      int j = sw * 64 + t;
      acc |= basep[(size_t)j * 16 + w];
    }
  }
  neighbits[gid] = acc;
}

// ------------------------------------------------------------ projection
// q (pre-scaled by 1/sqrt(5)), k, v' = (feats@Wv)@Wo   (all f32)
__global__ void k_proj(const float* __restrict__ feats,
                       const float* __restrict__ Wq, const float* __restrict__ Wk,
                       const float* __restrict__ Wv, const float* __restrict__ Wo,
                       float* __restrict__ qs, float* __restrict__ ks,
                       float* __restrict__ vps) {
  int node = blockIdx.x * blockDim.x + threadIdx.x;
  if (node >= BB * NN) return;
  float f[DD];
  #pragma unroll
  for (int d = 0; d < DD; ++d) f[d] = feats[node * DD + d];
  float v[DD];
  #pragma unroll
  for (int e = 0; e < DD; ++e) {
    float aq = 0.f, ak = 0.f, av = 0.f;
    #pragma unroll
    for (int d = 0; d < DD; ++d) {
      aq += f[d] * Wq[d * DD + e];
      ak += f[d] * Wk[d * DD + e];
      av += f[d] * Wv[d * DD + e];
    }
    qs[node * DD + e] = aq * 0.4472135954999579f;  // 1/sqrt(5)
    ks[node * DD + e] = ak;
    v[e] = av;
  }
  #pragma unroll
  for (int e = 0; e < DD; ++e) {
    float a = 0.f;
    #pragma unroll
    for (int d = 0; d < DD; ++d) a += v[d] * Wo[d * DD + e];
    vps[node * DD + e] = a;
  }
}

// ------------------------------------------------------------- attention
__global__ __launch_bounds__(256) void k_attn(
    const float* __restrict__ qs, const float* __restrict__ ks,
    const float* __restrict__ vps, const float* __restrict__ coors,
    const float* __restrict__ feats,
    const float* __restrict__ wr1, const float* __restrict__ br1,
    const float* __restrict__ wr2, const float* __restrict__ br2,
    const u64* __restrict__ neighbits, float* __restrict__ pooled) {
  __shared__ float kkL[NN * DD];
  __shared__ float vpL[NN * DD];
  __shared__ float coL[NN * 3];
  __shared__ float poolL[DD];
  int b = blockIdx.x >> 6;      // 64 chunks of 16 rows per batch
  int chunk = blockIdx.x & 63;
  int tid = threadIdx.x;
  for (int idx = tid; idx < NN * DD; idx += 256) {
    kkL[idx] = ks[b * NN * DD + idx];
    vpL[idx] = vps[b * NN * DD + idx];
  }
  for (int idx = tid; idx < NN * 3; idx += 256) coL[idx] = coors[b * NN * 3 + idx];
  if (tid < DD) poolL[tid] = 0.0f;
  float wr1f[RH], br1f[RH], wr2f[RH];
  #pragma unroll
  for (int h = 0; h < RH; ++h) {
    wr1f[h] = wr1[h];
    br1f[h] = br1[h];
    wr2f[h] = wr2[h];
  }
  float br2f = br2[0];
  __syncthreads();

  int wave = tid >> 6, lane = tid & 63;
  for (int ii = 0; ii < 4; ++ii) {
    int i = chunk * 16 + wave * 4 + ii;
    const float* qp = qs + ((size_t)b * NN + i) * DD;
    float q0 = qp[0], q1 = qp[1], q2 = qp[2], q3 = qp[3], q4 = qp[4];
    float ci0 = coL[i * 3], ci1 = coL[i * 3 + 1], ci2 = coL[i * 3 + 2];
    const u64* nrow = neighbits + ((size_t)b * NN + i) * 16;
    float m = -1e9f, l = 0.0f;
    float a0 = 0.f, a1 = 0.f, a2 = 0.f, a3 = 0.f, a4 = 0.f;
    for (int it = 0; it < 16; ++it) {
      int j = it * 64 + lane;
      u64 nw = nrow[it];
      int on = (int)((nw >> lane) & 1ull);
      float cx = coL[j * 3] - ci0;
      float cy = coL[j * 3 + 1] - ci1;
      float cz = coL[j * 3 + 2] - ci2;
      float dist = sqrtf(cx * cx + cy * cy + cz * cz + 1e-8f);
      float rb = br2f;
      #pragma unroll
      for (int h = 0; h < RH; ++h)
        rb += fmaxf(dist * wr1f[h] + br1f[h], 0.0f) * wr2f[h];
      float s = q0 * kkL[j * DD] + q1 * kkL[j * DD + 1] + q2 * kkL[j * DD + 2] +
                q3 * kkL[j * DD + 3] + q4 * kkL[j * DD + 4] + rb;
      s = on ? s : -1e9f;
      float mn = fmaxf(m, s);
      float sc = __expf(m - mn);
      float p = __expf(s - mn);
      l = l * sc + p;
      a0 = a0 * sc + p * vpL[j * DD + 0];
      a1 = a1 * sc + p * vpL[j * DD + 1];
      a2 = a2 * sc + p * vpL[j * DD + 2];
      a3 = a3 * sc + p * vpL[j * DD + 3];
      a4 = a4 * sc + p * vpL[j * DD + 4];
      m = mn;
    }
    #pragma unroll
    for (int msk = 1; msk < 64; msk <<= 1) {
      float m2 = __shfl_xor(m, msk, 64);
      float l2 = __shfl_xor(l, msk, 64);
      float b0 = __shfl_xor(a0, msk, 64);
      float b1 = __shfl_xor(a1, msk, 64);
      float b2 = __shfl_xor(a2, msk, 64);
      float b3 = __shfl_xor(a3, msk, 64);
      float b4 = __shfl_xor(a4, msk, 64);
      float mn = fmaxf(m, m2);
      float s1 = __expf(m - mn), s2 = __expf(m2 - mn);
      l = l * s1 + l2 * s2;
      a0 = a0 * s1 + b0 * s2;
      a1 = a1 * s1 + b1 * s2;
      a2 = a2 * s1 + b2 * s2;
      a3 = a3 * s1 + b3 * s2;
      a4 = a4 * s1 + b4 * s2;
      m = mn;
    }
    if (lane == 0) {
      float inv = (l > 0.f) ? 1.0f / l : 0.0f;
      const float* fp = feats + ((size_t)b * NN + i) * DD;
      atomicAdd(&poolL[0], fp[0] + a0 * inv);
      atomicAdd(&poolL[1], fp[1] + a1 * inv);
      atomicAdd(&poolL[2], fp[2] + a2 * inv);
      atomicAdd(&poolL[3], fp[3] + a3 * inv);
      atomicAdd(&poolL[4], fp[4] + a4 * inv);
    }
  }
  __syncthreads();
  if (tid < DD) atomicAdd(&pooled[b * DD + tid], poolL[tid]);
}

// ---------------------------------------------------------------- MLP head
// OUTPUT IS F32 (reference output dtype float32 — round-2 bf16 write was the bug)
__global__ void k_mlp(const float* __restrict__ pooled,
                      const float* __restrict__ w1, const float* __restrict__ b1,
                      const float* __restrict__ w2, const float* __restrict__ b2,
                      float* __restrict__ out) {
  int b = blockIdx.x;
  int t = threadIdx.x;  // 128
  __shared__ float hL[128];
  float p[DD];
  #pragma unroll
  for (int d = 0; d < DD; ++d) p[d] = pooled[b * DD + d] * (1.0f / 1024.0f);
  float acc = b1[t];
  #pragma unroll
  for (int d = 0; d < DD; ++d) acc += p[d] * w1[d * 128 + t];
  hL[t] = fmaxf(acc, 0.0f);
  __syncthreads();
  if (t < 3) {
    float s = b2[t];
    for (int j = 0; j < 128; ++j) s += hL[j] * w2[j * 3 + t];
    out[b * 3 + t] = s;
  }
}

// ---------------------------------------------------------------- launch
extern "C" void kernel_launch(void* const* d_in, const int* in_sizes, int n_in,
                              void* d_out, int out_size, void* d_ws, size_t ws_size,
                              hipStream_t stream) {
  const void* adj = d_in[2];
  float* out = (float*)d_out;

  char* w = (char*)d_ws;
  int* flags = (int*)w;                              // 8 ints
  float* pooled = (float*)(w + 64);                  // 80 f32
  const size_t BITS_BYTES = (size_t)BB * NN * 16 * sizeof(u64);  // 2 MiB
  u64* adjbits = (u64*)(w + 512);
  u64* neighbits = (u64*)(w + 512 + BITS_BYTES);
  float* qs = (float*)(w + 512 + 2 * BITS_BYTES);
  float* ks = qs + (size_t)BB * NN * DD;
  float* vps = ks + (size_t)BB * NN * DD;
  float* cvt = vps + (size_t)BB * NN * DD;

  // converted f32 copies of all 14 float inputs
  static const int cvt_n[14] = {BB * NN * DD, BB * NN * 3, 25, 25, 25, 25,
                                RH, RH, RH, 1, DD * 128, 128, 128 * 3, 3};
  CvtArgs ca;
  float* dst[14];
  {
    float* p = cvt;
    for (int i = 0; i < 14; ++i) { dst[i] = p; p += cvt_n[i]; }
  }
  int src_idx[14] = {0, 1, 3, 4, 5, 6, 7, 8, 9, 10, 11, 12, 13, 14};
  for (int i = 0; i < 14; ++i) {
    ca.src[i] = d_in[src_idx[i]];
    ca.dst[i] = dst[i];
    ca.n[i] = cvt_n[i];
  }
  float* featsF = dst[0];
  float* coorsF = dst[1];
  float* WqF = dst[2];
  float* WkF = dst[3];
  float* WvF = dst[4];
  float* WoF = dst[5];
  float* wr1F = dst[6];
  float* br1F = dst[7];
  float* wr2F = dst[8];
  float* br2F = dst[9];
  float* w1F = dst[10];
  float* b1F = dst[11];
  float* w2F = dst[12];
  float* b2F = dst[13];

  k_init<<<1, 128, 0, stream>>>(flags, pooled);
  k_probe_float<<<(N_PROBE_WORDS + 255) / 256, 256, 0, stream>>>(
      (const unsigned int*)d_in[0], flags);
  k_probe_adj<<<512, 256, 0, stream>>>((const unsigned int*)adj, 1 << 20, flags);
  k_cvt<<<dim3((BB * NN * DD + 255) / 256, 14), 256, 0, stream>>>(ca, flags);
  k_pack<<<BB * NN * 16 / 256, 256, 0, stream>>>(adj, flags, adjbits);
  k_twohop<<<BB * NN * 16 / 256, 256, 0, stream>>>(adjbits, neighbits);
  k_proj<<<BB * NN / 256, 256, 0, stream>>>(featsF, WqF, WkF, WvF, WoF, qs, ks, vps);
  k_attn<<<BB * 64, 256, 0, stream>>>(qs, ks, vps, coorsF, featsF, wr1F, br1F,
                                      wr2F, br2F, neighbits, pooled);
  k_mlp<<<BB, 128, 0, stream>>>(pooled, w1F, b1F, w2F, b2F, out);
}

// Round 4
// 239.895 us; speedup vs baseline: 1.0278x; 1.0278x over previous
//
#include <hip/hip_runtime.h>
#include <hip/hip_bf16.h>

#define BB 16
#define NN 1024
#define DD 5
#define RH 8

typedef unsigned long long u64;
typedef unsigned int u32;
typedef __hip_bfloat16 bf16;

static __device__ __forceinline__ float tof(bf16 x) { return __bfloat162float(x); }

// flags layout (int) in ws: [0]=insane_cnt [1]=adj_non01 [2]=adj_nonpair [3]=adj_low3f80
#define N_PROBE_WORDS 8192

// ---------------------------------------------------------------- init
__global__ void k_init(int* flags, float* pooled) {
  int t = threadIdx.x;
  if (t < 8) flags[t] = 0;
  if (t < BB * DD) pooled[t] = 0.0f;
}

// ---------------------------------------------- fused dtype probes
// blocks 0..31: float-dtype probe on feats; blocks 32..: adjacency probe.
__global__ void k_probe(const u32* __restrict__ fw, const u32* __restrict__ aw,
                        int adj_nwords, int* flags) {
  if (blockIdx.x < 32) {
    int i = blockIdx.x * 256 + threadIdx.x;
    if (i >= N_PROBE_WORDS) return;
    u32 lo = fw[i] & 0xFFFFu;
    int e = (int)((lo >> 7) & 0xFFu);
    bool sane = (lo == 0u) || (e >= 90 && e <= 150);
    u64 mask = __ballot(!sane);
    if ((threadIdx.x & 63) == 0) atomicAdd(&flags[0], (int)__popcll(mask));
  } else {
    int idx = (blockIdx.x - 32) * 256 + threadIdx.x;
    int stride = (gridDim.x - 32) * 256;
    int non01 = 0, nonpair = 0, low3 = 0;
    for (int i = idx; i < adj_nwords; i += stride) {
      u32 x = aw[i];
      u32 lo = x & 0xFFFFu, hi = x >> 16;
      non01 |= (x > 1u);
      nonpair |= !((lo == 0u || lo == 0x3F80u) && (hi == 0u || hi == 0x3F80u));
      low3 |= (lo == 0x3F80u);
    }
    if (non01) atomicOr(&flags[1], 1);
    if (nonpair) atomicOr(&flags[2], 1);
    if (low3) atomicOr(&flags[3], 1);
  }
}

// ------------------------------------------------- convert all float inputs
struct CvtArgs {
  const void* src[14];
  float* dst[14];
  int n[14];
};
__global__ void k_cvt(CvtArgs a, const int* __restrict__ flags) {
  int which = blockIdx.y;
  int n = a.n[which];
  int i = blockIdx.x * 256 + threadIdx.x;
  if (i >= n) return;
  bool isf32 = flags[0] > (N_PROBE_WORDS / 4);
  float v = isf32 ? ((const float*)a.src[which])[i]
                  : tof(((const bf16*)a.src[which])[i]);
  a.dst[which][i] = v;
}

// ---------------------------------------------------------------- pack
// adjbits[(b*N+i)*16 + w] = 64 adjacency bits j = w*64 .. w*64+63. 16-B loads.
__global__ void k_pack(const void* __restrict__ adj, const int* __restrict__ flags,
                       u64* __restrict__ adjbits) {
  int gid = blockIdx.x * blockDim.x + threadIdx.x;
  if (gid >= BB * NN * 16) return;
  int w = gid & 15;
  long long row = gid >> 4;  // b*N + i
  long long base = row * NN + (long long)w * 64;  // element index
  // mode: 0=int32, 1=byte, 2=bf16, 3=f32
  int mode;
  if (!flags[1]) mode = 0;
  else if (!flags[2]) mode = flags[3] ? 2 : 3;
  else mode = 1;
  u64 bits = 0;
  if (mode == 3) {
    const uint4* p = (const uint4*)((const float*)adj + base);
    #pragma unroll
    for (int t = 0; t < 16; ++t) {
      uint4 x = p[t];
      if (x.x << 1) bits |= 1ull << (4 * t + 0);   // f32 nonzero (ignore -0.0)
      if (x.y << 1) bits |= 1ull << (4 * t + 1);
      if (x.z << 1) bits |= 1ull << (4 * t + 2);
      if (x.w << 1) bits |= 1ull << (4 * t + 3);
    }
  } else if (mode == 0) {
    const uint4* p = (const uint4*)((const u32*)adj + base);
    #pragma unroll
    for (int t = 0; t < 16; ++t) {
      uint4 x = p[t];
      if (x.x) bits |= 1ull << (4 * t + 0);
      if (x.y) bits |= 1ull << (4 * t + 1);
      if (x.z) bits |= 1ull << (4 * t + 2);
      if (x.w) bits |= 1ull << (4 * t + 3);
    }
  } else if (mode == 2) {
    const uint4* p = (const uint4*)((const unsigned short*)adj + base);
    #pragma unroll
    for (int t = 0; t < 8; ++t) {
      uint4 x = p[t];
      u32 c[4] = {x.x, x.y, x.z, x.w};
      #pragma unroll
      for (int q = 0; q < 4; ++q) {
        if ((c[q] & 0x7FFFu)) bits |= 1ull << (8 * t + 2 * q + 0);
        if ((c[q] >> 16) & 0x7FFFu) bits |= 1ull << (8 * t + 2 * q + 1);
      }
    }
  } else {
    const uint4* p = (const uint4*)((const unsigned char*)adj + base);
    #pragma unroll
    for (int t = 0; t < 4; ++t) {
      uint4 x = p[t];
      u32 c[4] = {x.x, x.y, x.z, x.w};
      #pragma unroll
      for (int q = 0; q < 4; ++q)
        #pragma unroll
        for (int bb = 0; bb < 4; ++bb)
          if ((c[q] >> (8 * bb)) & 0xFFu) bits |= 1ull << (16 * t + 4 * q + bb);
    }
  }
  adjbits[gid] = bits;
}

// -------------------------------------------------------------- two-hop
// 4 threads per row; each owns 4 of the 16 output words. Row bits scanned
// once per thread; neighbor rows gathered as 32-B slices.
__global__ void k_twohop(const u64* __restrict__ adjbits, u64* __restrict__ neighbits) {
  int t = blockIdx.x * 256 + threadIdx.x;
  if (t >= BB * NN * 4) return;
  int part = t & 3;
  int row = t >> 2;  // b*N + i
  int b = row >> 10;
  int i = row & (NN - 1);
  const u64* rowp = adjbits + (size_t)row * 16;
  u64 rw[16];
  #pragma unroll
  for (int s = 0; s < 16; ++s) rw[s] = rowp[s];
  int w0 = part * 4;
  u64 acc0 = rw[w0], acc1 = rw[w0 + 1], acc2 = rw[w0 + 2], acc3 = rw[w0 + 3];
  int selfw = i >> 6;
  if ((selfw >> 2) == part) {
    u64 bit = 1ull << (i & 63);
    int k = selfw & 3;
    if (k == 0) acc0 |= bit;
    else if (k == 1) acc1 |= bit;
    else if (k == 2) acc2 |= bit;
    else acc3 |= bit;
  }
  const u64* basep = adjbits + (size_t)b * NN * 16;
  for (int sw = 0; sw < 16; ++sw) {
    u64 bits = rw[sw];
    while (bits) {
      int tt = __ffsll(bits) - 1;
      bits &= bits - 1;
      const u64* nrow = basep + ((size_t)(sw * 64 + tt) * 16 + w0);
      acc0 |= nrow[0];
      acc1 |= nrow[1];
      acc2 |= nrow[2];
      acc3 |= nrow[3];
    }
  }
  u64* o = neighbits + (size_t)row * 16 + w0;
  o[0] = acc0; o[1] = acc1; o[2] = acc2; o[3] = acc3;
}

// ------------------------------------------------------------- attention
// Fused projection + attention. j-sweep outer, 4 query rows per wave inner
// (amortizes the 13 LDS reads/j 4x). Per-lane order over it is identical to
// the round-3 kernel -> same numerics.
__global__ __launch_bounds__(256) void k_attn(
    const float* __restrict__ feats, const float* __restrict__ coors,
    const float* __restrict__ Wq, const float* __restrict__ Wk,
    const float* __restrict__ Wv, const float* __restrict__ Wo,
    const float* __restrict__ wr1, const float* __restrict__ br1,
    const float* __restrict__ wr2, const float* __restrict__ br2,
    const u64* __restrict__ neighbits, float* __restrict__ pooled) {
  __shared__ float kkL[NN * DD];
  __shared__ float vpL[NN * DD];
  __shared__ float coL[NN * 3];
  __shared__ float wqL[25], wkL[25], wvL[25], woL[25];
  __shared__ float qL[16 * DD];
  __shared__ float poolL[DD];
  int b = blockIdx.x >> 6;
  int chunk = blockIdx.x & 63;
  int tid = threadIdx.x;
  if (tid < 25) {
    wqL[tid] = Wq[tid]; wkL[tid] = Wk[tid]; wvL[tid] = Wv[tid]; woL[tid] = Wo[tid];
  }
  if (tid < DD) poolL[tid] = 0.0f;
  __syncthreads();
  // stage k, v' = (f@Wv)@Wo into LDS
  for (int n = tid; n < NN; n += 256) {
    const float* fp = feats + ((size_t)b * NN + n) * DD;
    float f0 = fp[0], f1 = fp[1], f2 = fp[2], f3 = fp[3], f4 = fp[4];
    float tv[DD];
    #pragma unroll
    for (int e = 0; e < DD; ++e) {
      kkL[n * DD + e] = f0 * wkL[e] + f1 * wkL[5 + e] + f2 * wkL[10 + e] +
                        f3 * wkL[15 + e] + f4 * wkL[20 + e];
      tv[e] = f0 * wvL[e] + f1 * wvL[5 + e] + f2 * wvL[10 + e] +
              f3 * wvL[15 + e] + f4 * wvL[20 + e];
    }
    #pragma unroll
    for (int e = 0; e < DD; ++e)
      vpL[n * DD + e] = tv[0] * woL[e] + tv[1] * woL[5 + e] + tv[2] * woL[10 + e] +
                        tv[3] * woL[15 + e] + tv[4] * woL[20 + e];
  }
  for (int idx = tid; idx < NN * 3; idx += 256) coL[idx] = coors[b * NN * 3 + idx];
  // q for this chunk's 16 rows (pre-scaled by 1/sqrt(5))
  if (tid < 16) {
    int i = chunk * 16 + tid;
    const float* fp = feats + ((size_t)b * NN + i) * DD;
    float f0 = fp[0], f1 = fp[1], f2 = fp[2], f3 = fp[3], f4 = fp[4];
    #pragma unroll
    for (int e = 0; e < DD; ++e)
      qL[tid * DD + e] = (f0 * wqL[e] + f1 * wqL[5 + e] + f2 * wqL[10 + e] +
                          f3 * wqL[15 + e] + f4 * wqL[20 + e]) * 0.4472135954999579f;
  }
  float wr1f[RH], br1f[RH], wr2f[RH];
  #pragma unroll
  for (int h = 0; h < RH; ++h) {
    wr1f[h] = wr1[h]; br1f[h] = br1[h]; wr2f[h] = wr2[h];
  }
  float br2f = br2[0];
  __syncthreads();

  int wave = tid >> 6, lane = tid & 63;
  int i0 = chunk * 16 + wave * 4;
  float q[4][DD], ci[4][3], m[4], l[4], A[4][DD];
  #pragma unroll
  for (int r = 0; r < 4; ++r) {
    #pragma unroll
    for (int e = 0; e < DD; ++e) q[r][e] = qL[(wave * 4 + r) * DD + e];
    #pragma unroll
    for (int c = 0; c < 3; ++c) ci[r][c] = coL[(i0 + r) * 3 + c];
    m[r] = -1e9f; l[r] = 0.0f;
    #pragma unroll
    for (int e = 0; e < DD; ++e) A[r][e] = 0.0f;
  }
  const u64* nb = neighbits + ((size_t)b * NN + i0) * 16;
  for (int it = 0; it < 16; ++it) {
    int j = it * 64 + lane;
    float k0 = kkL[j * DD], k1 = kkL[j * DD + 1], k2 = kkL[j * DD + 2],
          k3 = kkL[j * DD + 3], k4 = kkL[j * DD + 4];
    float v0 = vpL[j * DD], v1 = vpL[j * DD + 1], v2 = vpL[j * DD + 2],
          v3 = vpL[j * DD + 3], v4 = vpL[j * DD + 4];
    float jx = coL[j * 3], jy = coL[j * 3 + 1], jz = coL[j * 3 + 2];
    u64 nw[4];
    #pragma unroll
    for (int r = 0; r < 4; ++r) nw[r] = nb[r * 16 + it];
    #pragma unroll
    for (int r = 0; r < 4; ++r) {
      float cx = jx - ci[r][0], cy = jy - ci[r][1], cz = jz - ci[r][2];
      float dist = sqrtf(cx * cx + cy * cy + cz * cz + 1e-8f);
      float rb = br2f;
      #pragma unroll
      for (int h = 0; h < RH; ++h)
        rb += fmaxf(dist * wr1f[h] + br1f[h], 0.0f) * wr2f[h];
      float s = q[r][0] * k0 + q[r][1] * k1 + q[r][2] * k2 + q[r][3] * k3 +
                q[r][4] * k4 + rb;
      int on = (int)((nw[r] >> lane) & 1ull);
      s = on ? s : -1e9f;
      float mn = fmaxf(m[r], s);
      float sc = __expf(m[r] - mn);
      float p = __expf(s - mn);
      l[r] = l[r] * sc + p;
      A[r][0] = A[r][0] * sc + p * v0;
      A[r][1] = A[r][1] * sc + p * v1;
      A[r][2] = A[r][2] * sc + p * v2;
      A[r][3] = A[r][3] * sc + p * v3;
      A[r][4] = A[r][4] * sc + p * v4;
      m[r] = mn;
    }
  }
  #pragma unroll
  for (int msk = 1; msk < 64; msk <<= 1) {
    #pragma unroll
    for (int r = 0; r < 4; ++r) {
      float m2 = __shfl_xor(m[r], msk, 64);
      float l2 = __shfl_xor(l[r], msk, 64);
      float b0 = __shfl_xor(A[r][0], msk, 64);
      float b1 = __shfl_xor(A[r][1], msk, 64);
      float b2 = __shfl_xor(A[r][2], msk, 64);
      float b3 = __shfl_xor(A[r][3], msk, 64);
      float b4 = __shfl_xor(A[r][4], msk, 64);
      float mn = fmaxf(m[r], m2);
      float s1 = __expf(m[r] - mn), s2 = __expf(m2 - mn);
      l[r] = l[r] * s1 + l2 * s2;
      A[r][0] = A[r][0] * s1 + b0 * s2;
      A[r][1] = A[r][1] * s1 + b1 * s2;
      A[r][2] = A[r][2] * s1 + b2 * s2;
      A[r][3] = A[r][3] * s1 + b3 * s2;
      A[r][4] = A[r][4] * s1 + b4 * s2;
      m[r] = mn;
    }
  }
  if (lane == 0) {
    #pragma unroll
    for (int r = 0; r < 4; ++r) {
      float inv = (l[r] > 0.f) ? 1.0f / l[r] : 0.0f;
      const float* fp = feats + ((size_t)b * NN + i0 + r) * DD;
      atomicAdd(&poolL[0], fp[0] + A[r][0] * inv);
      atomicAdd(&poolL[1], fp[1] + A[r][1] * inv);
      atomicAdd(&poolL[2], fp[2] + A[r][2] * inv);
      atomicAdd(&poolL[3], fp[3] + A[r][3] * inv);
      atomicAdd(&poolL[4], fp[4] + A[r][4] * inv);
    }
  }
  __syncthreads();
  if (tid < DD) atomicAdd(&pooled[b * DD + tid], poolL[tid]);
}

// ---------------------------------------------------------------- MLP head
__global__ void k_mlp(const float* __restrict__ pooled,
                      const float* __restrict__ w1, const float* __restrict__ b1,
                      const float* __restrict__ w2, const float* __restrict__ b2,
                      float* __restrict__ out) {
  int b = blockIdx.x;
  int t = threadIdx.x;  // 128
  __shared__ float hL[128];
  float p[DD];
  #pragma unroll
  for (int d = 0; d < DD; ++d) p[d] = pooled[b * DD + d] * (1.0f / 1024.0f);
  float acc = b1[t];
  #pragma unroll
  for (int d = 0; d < DD; ++d) acc += p[d] * w1[d * 128 + t];
  hL[t] = fmaxf(acc, 0.0f);
  __syncthreads();
  if (t < 3) {
    float s = b2[t];
    for (int j = 0; j < 128; ++j) s += hL[j] * w2[j * 3 + t];
    out[b * 3 + t] = s;
  }
}

// ---------------------------------------------------------------- launch
extern "C" void kernel_launch(void* const* d_in, const int* in_sizes, int n_in,
                              void* d_out, int out_size, void* d_ws, size_t ws_size,
                              hipStream_t stream) {
  const void* adj = d_in[2];
  float* out = (float*)d_out;

  char* w = (char*)d_ws;
  int* flags = (int*)w;                              // 8 ints
  float* pooled = (float*)(w + 64);                  // 80 f32
  const size_t BITS_BYTES = (size_t)BB * NN * 16 * sizeof(u64);  // 2 MiB
  u64* adjbits = (u64*)(w + 512);
  u64* neighbits = (u64*)(w + 512 + BITS_BYTES);
  float* cvt = (float*)(w + 512 + 2 * BITS_BYTES);

  static const int cvt_n[14] = {BB * NN * DD, BB * NN * 3, 25, 25, 25, 25,
                                RH, RH, RH, 1, DD * 128, 128, 128 * 3, 3};
  CvtArgs ca;
  float* dst[14];
  {
    float* p = cvt;
    for (int i = 0; i < 14; ++i) { dst[i] = p; p += cvt_n[i]; }
  }
  int src_idx[14] = {0, 1, 3, 4, 5, 6, 7, 8, 9, 10, 11, 12, 13, 14};
  for (int i = 0; i < 14; ++i) {
    ca.src[i] = d_in[src_idx[i]];
    ca.dst[i] = dst[i];
    ca.n[i] = cvt_n[i];
  }

  k_init<<<1, 128, 0, stream>>>(flags, pooled);
  k_probe<<<32 + 512, 256, 0, stream>>>((const u32*)d_in[0], (const u32*)adj,
                                        1 << 20, flags);
  k_cvt<<<dim3((BB * NN * DD + 255) / 256, 14), 256, 0, stream>>>(ca, flags);
  k_pack<<<BB * NN * 16 / 256, 256, 0, stream>>>(adj, flags, adjbits);
  k_twohop<<<BB * NN * 4 / 256, 256, 0, stream>>>(adjbits, neighbits);
  k_attn<<<BB * 64, 256, 0, stream>>>(dst[0], dst[1], dst[2], dst[3], dst[4],
                                      dst[5], dst[6], dst[7], dst[8], dst[9],
                                      neighbits, pooled);
  k_mlp<<<BB, 128, 0, stream>>>(pooled, dst[10], dst[11], dst[12], dst[13], out);
}

// Round 5
// 218.598 us; speedup vs baseline: 1.1279x; 1.0974x over previous
//
#include <hip/hip_runtime.h>
#include <hip/hip_bf16.h>

#define BB 16
#define NN 1024
#define DD 5
#define RH 8

typedef unsigned long long u64;
typedef unsigned int u32;
typedef __hip_bfloat16 bf16;

static __device__ __forceinline__ float tof(bf16 x) { return __bfloat162float(x); }

// flags layout (int) in ws: [0]=insane_cnt [1]=adj_non01 [2]=adj_nonpair [3]=adj_low3f80
#define N_PROBE_WORDS 8192

// ---------------------------------------------------------------- init
__global__ void k_init(int* flags, float* pooled) {
  int t = threadIdx.x;
  if (t < 8) flags[t] = 0;
  if (t < BB * DD) pooled[t] = 0.0f;
}

// ---------------------------------------------- fused dtype probes
__global__ void k_probe(const u32* __restrict__ fw, const u32* __restrict__ aw,
                        int adj_nwords, int* flags) {
  if (blockIdx.x < 32) {
    int i = blockIdx.x * 256 + threadIdx.x;
    if (i >= N_PROBE_WORDS) return;
    u32 lo = fw[i] & 0xFFFFu;
    int e = (int)((lo >> 7) & 0xFFu);
    bool sane = (lo == 0u) || (e >= 90 && e <= 150);
    u64 mask = __ballot(!sane);
    if ((threadIdx.x & 63) == 0) atomicAdd(&flags[0], (int)__popcll(mask));
  } else {
    int idx = (blockIdx.x - 32) * 256 + threadIdx.x;
    int stride = (gridDim.x - 32) * 256;
    int non01 = 0, nonpair = 0, low3 = 0;
    for (int i = idx; i < adj_nwords; i += stride) {
      u32 x = aw[i];
      u32 lo = x & 0xFFFFu, hi = x >> 16;
      non01 |= (x > 1u);
      nonpair |= !((lo == 0u || lo == 0x3F80u) && (hi == 0u || hi == 0x3F80u));
      low3 |= (lo == 0x3F80u);
    }
    if (non01) atomicOr(&flags[1], 1);
    if (nonpair) atomicOr(&flags[2], 1);
    if (low3) atomicOr(&flags[3], 1);
  }
}

// ------------------------------------------------- convert all float inputs
struct CvtArgs {
  const void* src[14];
  float* dst[14];
  int n[14];
};
__global__ void k_cvt(CvtArgs a, const int* __restrict__ flags) {
  int which = blockIdx.y;
  int n = a.n[which];
  int i = blockIdx.x * 256 + threadIdx.x;
  if (i >= n) return;
  bool isf32 = flags[0] > (N_PROBE_WORDS / 4);
  float v = isf32 ? ((const float*)a.src[which])[i]
                  : tof(((const bf16*)a.src[which])[i]);
  a.dst[which][i] = v;
}

// ---------------------------------------------------------------- pack
__global__ void k_pack(const void* __restrict__ adj, const int* __restrict__ flags,
                       u64* __restrict__ adjbits) {
  int gid = blockIdx.x * blockDim.x + threadIdx.x;
  if (gid >= BB * NN * 16) return;
  int w = gid & 15;
  long long row = gid >> 4;
  long long base = row * NN + (long long)w * 64;
  int mode;
  if (!flags[1]) mode = 0;
  else if (!flags[2]) mode = flags[3] ? 2 : 3;
  else mode = 1;
  u64 bits = 0;
  if (mode == 3) {
    const uint4* p = (const uint4*)((const float*)adj + base);
    #pragma unroll
    for (int t = 0; t < 16; ++t) {
      uint4 x = p[t];
      if (x.x << 1) bits |= 1ull << (4 * t + 0);
      if (x.y << 1) bits |= 1ull << (4 * t + 1);
      if (x.z << 1) bits |= 1ull << (4 * t + 2);
      if (x.w << 1) bits |= 1ull << (4 * t + 3);
    }
  } else if (mode == 0) {
    const uint4* p = (const uint4*)((const u32*)adj + base);
    #pragma unroll
    for (int t = 0; t < 16; ++t) {
      uint4 x = p[t];
      if (x.x) bits |= 1ull << (4 * t + 0);
      if (x.y) bits |= 1ull << (4 * t + 1);
      if (x.z) bits |= 1ull << (4 * t + 2);
      if (x.w) bits |= 1ull << (4 * t + 3);
    }
  } else if (mode == 2) {
    const uint4* p = (const uint4*)((const unsigned short*)adj + base);
    #pragma unroll
    for (int t = 0; t < 8; ++t) {
      uint4 x = p[t];
      u32 c[4] = {x.x, x.y, x.z, x.w};
      #pragma unroll
      for (int q = 0; q < 4; ++q) {
        if ((c[q] & 0x7FFFu)) bits |= 1ull << (8 * t + 2 * q + 0);
        if ((c[q] >> 16) & 0x7FFFu) bits |= 1ull << (8 * t + 2 * q + 1);
      }
    }
  } else {
    const uint4* p = (const uint4*)((const unsigned char*)adj + base);
    #pragma unroll
    for (int t = 0; t < 4; ++t) {
      uint4 x = p[t];
      u32 c[4] = {x.x, x.y, x.z, x.w};
      #pragma unroll
      for (int q = 0; q < 4; ++q)
        #pragma unroll
        for (int bb = 0; bb < 4; ++bb)
          if ((c[q] >> (8 * bb)) & 0xFFu) bits |= 1ull << (16 * t + 4 * q + bb);
    }
  }
  adjbits[gid] = bits;
}

// -------------------------------------------------------------- two-hop
// One wave per row. Cooperative bit-enumeration into an LDS worklist, then
// 4 lane-groups gather neighbor rows (coalesced 128B) and OR-fold.
__global__ __launch_bounds__(256) void k_twohop(const u64* __restrict__ adjbits,
                                                u64* __restrict__ neighbits) {
  __shared__ unsigned short listL[4][NN];
  int wave = threadIdx.x >> 6, lane = threadIdx.x & 63;
  int row = blockIdx.x * 4 + wave;  // b*N + i
  int b = row >> 10;
  int i = row & (NN - 1);
  int w = lane & 15;
  const u64* rowp = adjbits + (size_t)row * 16;
  u64 rw = rowp[w];
  unsigned short* list = listL[wave];
  int cnt = 0;
  #pragma unroll
  for (int sw = 0; sw < 16; ++sw) {
    u64 bits = __shfl(rw, sw, 64);
    int mybit = (int)((bits >> lane) & 1ull);
    int pre = __popcll(bits & ((1ull << lane) - 1ull));
    if (mybit) list[cnt + pre] = (unsigned short)(sw * 64 + lane);
    cnt += __popcll(bits);
  }
  __syncthreads();
  u64 acc = rw;
  if (w == (i >> 6)) acc |= 1ull << (i & 63);
  int g = lane >> 4;
  const u64* basep = adjbits + (size_t)b * NN * 16;
  for (int n = g; n < cnt; n += 4) {
    int j = list[n];
    acc |= basep[(size_t)j * 16 + w];
  }
  acc |= __shfl_xor(acc, 16, 64);
  acc |= __shfl_xor(acc, 32, 64);
  if (lane < 16) neighbits[(size_t)row * 16 + lane] = acc;
}

// ------------------------------------------------------------- attention
// Fused proj + attention. 8 query rows per wave (32/block), j-sweep outer.
// Radial MLP has zero biases in this problem -> rbias = C*d + b2 (one fma);
// generic fallback kept behind a wave-uniform flag.
__global__ __launch_bounds__(256, 2) void k_attn(
    const float* __restrict__ feats, const float* __restrict__ coors,
    const float* __restrict__ Wq, const float* __restrict__ Wk,
    const float* __restrict__ Wv, const float* __restrict__ Wo,
    const float* __restrict__ wr1, const float* __restrict__ br1,
    const float* __restrict__ wr2, const float* __restrict__ br2,
    const u64* __restrict__ neighbits, float* __restrict__ pooled) {
  __shared__ __align__(16) float kvL[NN * 12];  // [k0..k4, v0..v4, pad, pad]
  __shared__ float coL[NN * 3];
  __shared__ float wqL[25], wkL[25], wvL[25], woL[25];
  __shared__ float qL[32 * DD];
  __shared__ float poolL[DD];
  __shared__ float sC[2];
  __shared__ int sFast;
  int b = blockIdx.x >> 5;
  int chunk = blockIdx.x & 31;
  int tid = threadIdx.x;
  if (tid < 25) {
    wqL[tid] = Wq[tid]; wkL[tid] = Wk[tid]; wvL[tid] = Wv[tid]; woL[tid] = Wo[tid];
  }
  if (tid < DD) poolL[tid] = 0.0f;
  if (tid == 0) {
    float c = 0.0f;
    int ok = 1;
    #pragma unroll
    for (int h = 0; h < RH; ++h) {
      float w1h = wr1[h];
      if (br1[h] != 0.0f) ok = 0;
      if (w1h > 0.0f) c += w1h * wr2[h];
    }
    sC[0] = c; sFast = ok;
  }
  __syncthreads();
  // stage k, v' = (f@Wv)@Wo into LDS (packed 12-stride)
  for (int n = tid; n < NN; n += 256) {
    const float* fp = feats + ((size_t)b * NN + n) * DD;
    float f0 = fp[0], f1 = fp[1], f2 = fp[2], f3 = fp[3], f4 = fp[4];
    float tv[DD];
    #pragma unroll
    for (int e = 0; e < DD; ++e) {
      kvL[n * 12 + e] = f0 * wkL[e] + f1 * wkL[5 + e] + f2 * wkL[10 + e] +
                        f3 * wkL[15 + e] + f4 * wkL[20 + e];
      tv[e] = f0 * wvL[e] + f1 * wvL[5 + e] + f2 * wvL[10 + e] +
              f3 * wvL[15 + e] + f4 * wvL[20 + e];
    }
    #pragma unroll
    for (int e = 0; e < DD; ++e)
      kvL[n * 12 + 5 + e] = tv[0] * woL[e] + tv[1] * woL[5 + e] +
                            tv[2] * woL[10 + e] + tv[3] * woL[15 + e] +
                            tv[4] * woL[20 + e];
  }
  for (int idx = tid; idx < NN * 3; idx += 256) coL[idx] = coors[b * NN * 3 + idx];
  if (tid < 32) {
    int i = chunk * 32 + tid;
    const float* fp = feats + ((size_t)b * NN + i) * DD;
    float f0 = fp[0], f1 = fp[1], f2 = fp[2], f3 = fp[3], f4 = fp[4];
    #pragma unroll
    for (int e = 0; e < DD; ++e)
      qL[tid * DD + e] = (f0 * wqL[e] + f1 * wqL[5 + e] + f2 * wqL[10 + e] +
                          f3 * wqL[15 + e] + f4 * wqL[20 + e]) * 0.4472135954999579f;
  }
  float wr1f[RH], br1f[RH], wr2f[RH];
  #pragma unroll
  for (int h = 0; h < RH; ++h) {
    wr1f[h] = wr1[h]; br1f[h] = br1[h]; wr2f[h] = wr2[h];
  }
  float br2f = br2[0];
  __syncthreads();

  int wave = tid >> 6, lane = tid & 63;
  int i0 = chunk * 32 + wave * 8;
  float q[8][DD], ci[8][3], m[8], l[8], A[8][DD];
  #pragma unroll
  for (int r = 0; r < 8; ++r) {
    #pragma unroll
    for (int e = 0; e < DD; ++e) q[r][e] = qL[(wave * 8 + r) * DD + e];
    #pragma unroll
    for (int c = 0; c < 3; ++c) ci[r][c] = coL[(i0 + r) * 3 + c];
    m[r] = -1e9f; l[r] = 0.0f;
    #pragma unroll
    for (int e = 0; e < DD; ++e) A[r][e] = 0.0f;
  }
  const u64* nb = neighbits + ((size_t)b * NN + i0) * 16;
  float Cf = sC[0];
  int fast = sFast;
  for (int it = 0; it < 16; ++it) {
    int j = it * 64 + lane;
    float4 ka = *(const float4*)&kvL[j * 12];      // k0..k3
    float4 kb = *(const float4*)&kvL[j * 12 + 4];  // k4, v0..v2
    float4 kc = *(const float4*)&kvL[j * 12 + 8];  // v3, v4, -, -
    float jx = coL[j * 3], jy = coL[j * 3 + 1], jz = coL[j * 3 + 2];
    u64 nw[8];
    #pragma unroll
    for (int r = 0; r < 8; ++r) nw[r] = nb[r * 16 + it];
    if (fast) {
      #pragma unroll
      for (int r = 0; r < 8; ++r) {
        float cx = jx - ci[r][0], cy = jy - ci[r][1], cz = jz - ci[r][2];
        float dist = sqrtf(fmaf(cx, cx, fmaf(cy, cy, fmaf(cz, cz, 1e-8f))));
        float s = fmaf(q[r][0], ka.x, br2f);
        s = fmaf(q[r][1], ka.y, s);
        s = fmaf(q[r][2], ka.z, s);
        s = fmaf(q[r][3], ka.w, s);
        s = fmaf(q[r][4], kb.x, s);
        s = fmaf(Cf, dist, s);
        int on = (int)((nw[r] >> lane) & 1ull);
        s = on ? s : -1e9f;
        float mn = fmaxf(m[r], s);
        float sc = __expf(m[r] - mn);
        float p = __expf(s - mn);
        l[r] = fmaf(l[r], sc, p);
        A[r][0] = fmaf(A[r][0], sc, p * kb.y);
        A[r][1] = fmaf(A[r][1], sc, p * kb.z);
        A[r][2] = fmaf(A[r][2], sc, p * kb.w);
        A[r][3] = fmaf(A[r][3], sc, p * kc.x);
        A[r][4] = fmaf(A[r][4], sc, p * kc.y);
        m[r] = mn;
      }
    } else {
      #pragma unroll
      for (int r = 0; r < 8; ++r) {
        float cx = jx - ci[r][0], cy = jy - ci[r][1], cz = jz - ci[r][2];
        float dist = sqrtf(fmaf(cx, cx, fmaf(cy, cy, fmaf(cz, cz, 1e-8f))));
        float rb = br2f;
        #pragma unroll
        for (int h = 0; h < RH; ++h)
          rb += fmaxf(dist * wr1f[h] + br1f[h], 0.0f) * wr2f[h];
        float s = fmaf(q[r][0], ka.x, rb);
        s = fmaf(q[r][1], ka.y, s);
        s = fmaf(q[r][2], ka.z, s);
        s = fmaf(q[r][3], ka.w, s);
        s = fmaf(q[r][4], kb.x, s);
        int on = (int)((nw[r] >> lane) & 1ull);
        s = on ? s : -1e9f;
        float mn = fmaxf(m[r], s);
        float sc = __expf(m[r] - mn);
        float p = __expf(s - mn);
        l[r] = fmaf(l[r], sc, p);
        A[r][0] = fmaf(A[r][0], sc, p * kb.y);
        A[r][1] = fmaf(A[r][1], sc, p * kb.z);
        A[r][2] = fmaf(A[r][2], sc, p * kb.w);
        A[r][3] = fmaf(A[r][3], sc, p * kc.x);
        A[r][4] = fmaf(A[r][4], sc, p * kc.y);
        m[r] = mn;
      }
    }
  }
  #pragma unroll
  for (int msk = 1; msk < 64; msk <<= 1) {
    #pragma unroll
    for (int r = 0; r < 8; ++r) {
      float m2 = __shfl_xor(m[r], msk, 64);
      float l2 = __shfl_xor(l[r], msk, 64);
      float b0 = __shfl_xor(A[r][0], msk, 64);
      float b1 = __shfl_xor(A[r][1], msk, 64);
      float b2 = __shfl_xor(A[r][2], msk, 64);
      float b3 = __shfl_xor(A[r][3], msk, 64);
      float b4 = __shfl_xor(A[r][4], msk, 64);
      float mn = fmaxf(m[r], m2);
      float s1 = __expf(m[r] - mn), s2 = __expf(m2 - mn);
      l[r] = l[r] * s1 + l2 * s2;
      A[r][0] = A[r][0] * s1 + b0 * s2;
      A[r][1] = A[r][1] * s1 + b1 * s2;
      A[r][2] = A[r][2] * s1 + b2 * s2;
      A[r][3] = A[r][3] * s1 + b3 * s2;
      A[r][4] = A[r][4] * s1 + b4 * s2;
      m[r] = mn;
    }
  }
  if (lane == 0) {
    #pragma unroll
    for (int r = 0; r < 8; ++r) {
      float inv = (l[r] > 0.f) ? 1.0f / l[r] : 0.0f;
      const float* fp = feats + ((size_t)b * NN + i0 + r) * DD;
      atomicAdd(&poolL[0], fp[0] + A[r][0] * inv);
      atomicAdd(&poolL[1], fp[1] + A[r][1] * inv);
      atomicAdd(&poolL[2], fp[2] + A[r][2] * inv);
      atomicAdd(&poolL[3], fp[3] + A[r][3] * inv);
      atomicAdd(&poolL[4], fp[4] + A[r][4] * inv);
    }
  }
  __syncthreads();
  if (tid < DD) atomicAdd(&pooled[b * DD + tid], poolL[tid]);
}

// ---------------------------------------------------------------- MLP head
__global__ void k_mlp(const float* __restrict__ pooled,
                      const float* __restrict__ w1, const float* __restrict__ b1,
                      const float* __restrict__ w2, const float* __restrict__ b2,
                      float* __restrict__ out) {
  int b = blockIdx.x;
  int t = threadIdx.x;  // 128
  __shared__ float hL[128];
  float p[DD];
  #pragma unroll
  for (int d = 0; d < DD; ++d) p[d] = pooled[b * DD + d] * (1.0f / 1024.0f);
  float acc = b1[t];
  #pragma unroll
  for (int d = 0; d < DD; ++d) acc += p[d] * w1[d * 128 + t];
  hL[t] = fmaxf(acc, 0.0f);
  __syncthreads();
  if (t < 3) {
    float s = b2[t];
    for (int j = 0; j < 128; ++j) s += hL[j] * w2[j * 3 + t];
    out[b * 3 + t] = s;
  }
}

// ---------------------------------------------------------------- launch
extern "C" void kernel_launch(void* const* d_in, const int* in_sizes, int n_in,
                              void* d_out, int out_size, void* d_ws, size_t ws_size,
                              hipStream_t stream) {
  const void* adj = d_in[2];
  float* out = (float*)d_out;

  char* w = (char*)d_ws;
  int* flags = (int*)w;
  float* pooled = (float*)(w + 64);
  const size_t BITS_BYTES = (size_t)BB * NN * 16 * sizeof(u64);  // 2 MiB
  u64* adjbits = (u64*)(w + 512);
  u64* neighbits = (u64*)(w + 512 + BITS_BYTES);
  float* cvt = (float*)(w + 512 + 2 * BITS_BYTES);

  static const int cvt_n[14] = {BB * NN * DD, BB * NN * 3, 25, 25, 25, 25,
                                RH, RH, RH, 1, DD * 128, 128, 128 * 3, 3};
  CvtArgs ca;
  float* dst[14];
  {
    float* p = cvt;
    for (int i = 0; i < 14; ++i) { dst[i] = p; p += cvt_n[i]; }
  }
  int src_idx[14] = {0, 1, 3, 4, 5, 6, 7, 8, 9, 10, 11, 12, 13, 14};
  for (int i = 0; i < 14; ++i) {
    ca.src[i] = d_in[src_idx[i]];
    ca.dst[i] = dst[i];
    ca.n[i] = cvt_n[i];
  }

  k_init<<<1, 128, 0, stream>>>(flags, pooled);
  k_probe<<<32 + 512, 256, 0, stream>>>((const u32*)d_in[0], (const u32*)adj,
                                        1 << 20, flags);
  k_cvt<<<dim3((BB * NN * DD + 255) / 256, 14), 256, 0, stream>>>(ca, flags);
  k_pack<<<BB * NN * 16 / 256, 256, 0, stream>>>(adj, flags, adjbits);
  k_twohop<<<BB * NN / 4, 256, 0, stream>>>(adjbits, neighbits);
  k_attn<<<BB * 32, 256, 0, stream>>>(dst[0], dst[1], dst[2], dst[3], dst[4],
                                      dst[5], dst[6], dst[7], dst[8], dst[9],
                                      neighbits, pooled);
  k_mlp<<<BB, 128, 0, stream>>>(pooled, dst[10], dst[11], dst[12], dst[13], out);
}